// Round 2
// baseline (186.496 us; speedup 1.0000x reference)
//
#include <hip/hip_runtime.h>
#include <hip/hip_bf16.h>
#include <math.h>

#define EPS 1e-6f
#define TAU 1.0f

__device__ __forceinline__ float gd_loss_one(
        float px, float py, float pw, float ph, float pr,
        float tx, float ty, float tw, float th, float tr) {
    // pred sigma
    pw = fminf(fmaxf(pw, 1e-7f), 1e7f);
    ph = fminf(fmaxf(ph, 1e-7f), 1e7f);
    float pa = 0.25f * pw * pw;
    float pb = 0.25f * ph * ph;
    float ps, pc;
    __sincosf(pr, &ps, &pc);
    float p11 = pa * pc * pc + pb * ps * ps;
    float p12 = (pa - pb) * ps * pc;
    float p22 = pa * ps * ps + pb * pc * pc;
    // target sigma
    tw = fminf(fmaxf(tw, 1e-7f), 1e7f);
    th = fminf(fmaxf(th, 1e-7f), 1e7f);
    float ta = 0.25f * tw * tw;
    float tb = 0.25f * th * th;
    float ts, tc;
    __sincosf(tr, &ts, &tc);
    float t11 = ta * tc * tc + tb * ts * ts;
    float t12 = (ta - tb) * ts * tc;
    float t22 = ta * ts * ts + tb * tc * tc;

    float det_p = p11 * p22 - p12 * p12;
    float det_t = t11 * t22 - t12 * t12;

    float dx = px - tx;
    float dy = py - ty;

    float inv_det_t = __frcp_rn(det_t);
    float term1 = (t22 * dx * dx - 2.0f * t12 * dx * dy + t11 * dy * dy) * inv_det_t;
    float trace_term = (t22 * p11 - 2.0f * t12 * p12 + t11 * p22) * inv_det_t;
    float term2 = trace_term + __logf(det_t) - __logf(det_p);

    float dis = term1 + term2 - 2.0f;
    float kl = fmaxf(dis, EPS);
    return 1.0f - 1.0f / (TAU + sqrtf(kl));
}

// Each thread handles 4 boxes = 20 floats = 5 float4 loads per input array.
__global__ void __launch_bounds__(256) gd_loss_kernel4(
        const float4* __restrict__ pred4,
        const float4* __restrict__ tgt4,
        float4* __restrict__ out4, int nq) {
    int i = blockIdx.x * blockDim.x + threadIdx.x;
    if (i >= nq) return;

    float pf[20], tf[20];
    #pragma unroll
    for (int k = 0; k < 5; k++) {
        float4 v = pred4[(size_t)i * 5 + k];
        pf[4 * k] = v.x; pf[4 * k + 1] = v.y; pf[4 * k + 2] = v.z; pf[4 * k + 3] = v.w;
    }
    #pragma unroll
    for (int k = 0; k < 5; k++) {
        float4 v = tgt4[(size_t)i * 5 + k];
        tf[4 * k] = v.x; tf[4 * k + 1] = v.y; tf[4 * k + 2] = v.z; tf[4 * k + 3] = v.w;
    }

    float res[4];
    #pragma unroll
    for (int b = 0; b < 4; b++) {
        res[b] = gd_loss_one(pf[b * 5 + 0], pf[b * 5 + 1], pf[b * 5 + 2], pf[b * 5 + 3], pf[b * 5 + 4],
                             tf[b * 5 + 0], tf[b * 5 + 1], tf[b * 5 + 2], tf[b * 5 + 3], tf[b * 5 + 4]);
    }
    out4[i] = make_float4(res[0], res[1], res[2], res[3]);
}

// Scalar tail for n % 4 != 0 (not hit at N=4M, but correctness-safe).
__global__ void gd_loss_tail(
        const float* __restrict__ pred,
        const float* __restrict__ tgt,
        float* __restrict__ out, int start, int n) {
    int i = start + blockIdx.x * blockDim.x + threadIdx.x;
    if (i >= n) return;
    const float* p = pred + (size_t)i * 5;
    const float* t = tgt + (size_t)i * 5;
    out[i] = gd_loss_one(p[0], p[1], p[2], p[3], p[4],
                         t[0], t[1], t[2], t[3], t[4]);
}

extern "C" void kernel_launch(void* const* d_in, const int* in_sizes, int n_in,
                              void* d_out, int out_size, void* d_ws, size_t ws_size,
                              hipStream_t stream) {
    const float* pred = (const float*)d_in[0];
    const float* tgt  = (const float*)d_in[1];
    float* out = (float*)d_out;
    int n = out_size;  // N boxes

    int nq = n / 4;
    int rem = n - nq * 4;

    if (nq > 0) {
        int block = 256;
        int grid = (nq + block - 1) / block;
        gd_loss_kernel4<<<grid, block, 0, stream>>>(
            (const float4*)pred, (const float4*)tgt, (float4*)out, nq);
    }
    if (rem > 0) {
        gd_loss_tail<<<1, 64, 0, stream>>>(pred, tgt, out, nq * 4, n);
    }
}